// Round 1
// baseline (169.818 us; speedup 1.0000x reference)
//
#include <hip/hip_runtime.h>

#define NB 8
#define CIN 256
#define SD 512
#define HW 128
#define EPS 1e-5f

// ---------------- 1. style spatial mean: s[n,c] = mean(style[n,c,:,:]) ----------------
__global__ __launch_bounds__(256) void style_mean_k(const float* __restrict__ style,
                                                    float* __restrict__ s_ws) {
    int u = blockIdx.x * 256 + threadIdx.x;
    if (u >= NB * SD) return;
    const float* p = style + (size_t)u * 16;
    float a = 0.f;
#pragma unroll
    for (int k = 0; k < 16; ++k) a += p[k];
    s_ws[u] = a * (1.f / 16.f);
}

// ---------------- 2. dw kernel generation: dw[n,f,3,3] = conv(style, dw_w) + b --------
// f in [0,1024). One block per (f, n); 256 threads reduce over 512 style channels.
__global__ __launch_bounds__(256) void gen_dw_k(const float* __restrict__ style,
                                                const float* __restrict__ dww,
                                                const float* __restrict__ dwb,
                                                float* __restrict__ dw) {
    int f = blockIdx.x, n = blockIdx.y, t = threadIdx.x;
    float acc[9];
#pragma unroll
    for (int k = 0; k < 9; ++k) acc[k] = 0.f;
    for (int c = t; c < SD; c += 256) {
        const float4* sp = (const float4*)(style + ((size_t)n * SD + c) * 16);
        float st[16];
#pragma unroll
        for (int k = 0; k < 4; ++k) {
            float4 v = sp[k];
            st[k * 4 + 0] = v.x; st[k * 4 + 1] = v.y;
            st[k * 4 + 2] = v.z; st[k * 4 + 3] = v.w;
        }
        float4 w = *(const float4*)(dww + ((size_t)f * SD + c) * 4);
#pragma unroll
        for (int p = 0; p < 3; ++p)
#pragma unroll
            for (int q = 0; q < 3; ++q)
                acc[p * 3 + q] += st[p * 4 + q] * w.x + st[p * 4 + q + 1] * w.y
                                + st[(p + 1) * 4 + q] * w.z + st[(p + 1) * 4 + q + 1] * w.w;
    }
    __shared__ float red[4][9];
#pragma unroll
    for (int k = 0; k < 9; ++k)
#pragma unroll
        for (int off = 32; off; off >>= 1) acc[k] += __shfl_down(acc[k], off);
    if ((t & 63) == 0) {
#pragma unroll
        for (int k = 0; k < 9; ++k) red[t >> 6][k] = acc[k];
    }
    __syncthreads();
    if (t < 9)
        dw[((size_t)n * 1024 + f) * 9 + t] =
            red[0][t] + red[1][t] + red[2][t] + red[3][t] + dwb[f];
}

// ---------------- 3. pointwise kernels + bias: linear layers on s ---------------------
// u enumerates 8*(1024+256) outputs; 512-MAC dot product each (float4).
__global__ __launch_bounds__(256) void gen_pw_k(const float* __restrict__ s_ws,
                                                const float* __restrict__ pkw,
                                                const float* __restrict__ pkb,
                                                const float* __restrict__ pbw,
                                                const float* __restrict__ pbb,
                                                float* __restrict__ pwk,
                                                float* __restrict__ pwbias) {
    int u = blockIdx.x * 256 + threadIdx.x;
    if (u >= NB * 1280) return;
    int n = u / 1280;
    int j = u - n * 1280;
    bool isk = j < 1024;
    const float4* sv = (const float4*)(s_ws + (size_t)n * SD);
    const float4* wv = (const float4*)(isk ? (pkw + (size_t)j * SD)
                                           : (pbw + (size_t)(j - 1024) * SD));
    float a = 0.f;
    for (int k = 0; k < SD / 4; ++k) {
        float4 x = sv[k];
        float4 w = wv[k];
        a += x.x * w.x + x.y * w.y + x.z * w.z + x.w * w.w;
    }
    if (isk) pwk[(size_t)n * 1024 + j] = a + pkb[j];
    else     pwbias[(size_t)n * 256 + (j - 1024)] = a + pbb[j - 1024];
}

// ---------------- 4. instance-norm stats: mean & rsqrt(var+eps) per (n,c) -------------
__global__ __launch_bounds__(256) void inorm_stats_k(const float* __restrict__ pred,
                                                     float* __restrict__ meanv,
                                                     float* __restrict__ invv) {
    int bc = blockIdx.x;  // 0..2047 = n*256+c
    int t = threadIdx.x;
    const float4* p = (const float4*)(pred + (size_t)bc * HW * HW);
    float s = 0.f, ss = 0.f;
#pragma unroll
    for (int k = 0; k < 16; ++k) {
        float4 v = p[k * 256 + t];
        s  += v.x + v.y + v.z + v.w;
        ss += v.x * v.x + v.y * v.y + v.z * v.z + v.w * v.w;
    }
#pragma unroll
    for (int off = 32; off; off >>= 1) {
        s  += __shfl_down(s, off);
        ss += __shfl_down(ss, off);
    }
    __shared__ float ws4[4], wss4[4];
    if ((t & 63) == 0) { ws4[t >> 6] = s; wss4[t >> 6] = ss; }
    __syncthreads();
    if (t == 0) {
        float S  = ws4[0] + ws4[1] + ws4[2] + ws4[3];
        float SS = wss4[0] + wss4[1] + wss4[2] + wss4[3];
        float m = S * (1.f / (HW * HW));
        float var = SS * (1.f / (HW * HW)) - m * m;
        meanv[bc] = m;
        invv[bc] = rsqrtf(var + EPS);
    }
}

// ---------------- 5. fused: normalize + reflect-pad + grouped 3x3 + 1x1 + bias --------
// block = (n, g, 64x32 tile). LDS tile [4][66][34] (~36 KiB).
// thread: px = t&31 (col), rb = t>>5 (8-row block). Each thread: 8 pixels/channel-out.
__global__ __launch_bounds__(256) void adaconv_main_k(const float* __restrict__ pred,
                                                      const float* __restrict__ dw,
                                                      const float* __restrict__ pwk,
                                                      const float* __restrict__ pwb,
                                                      const float* __restrict__ meanv,
                                                      const float* __restrict__ invv,
                                                      float* __restrict__ out) {
    __shared__ float tile[4][66][34];
    __shared__ float wds[4][4][9];  // [o][ic][kh*3+kw]
    __shared__ float wpw[4][4];     // [o][i]
    __shared__ float wb[4];

    int b = blockIdx.x;             // 4096 blocks
    int tx0 = (b & 3) * 32;
    int ty0 = ((b >> 2) & 1) * 64;
    int g = (b >> 3) & 63;
    int n = b >> 9;
    int t = threadIdx.x;

    // weights -> LDS
    if (t < 144) {
        int o = t / 36, r = t - o * 36;
        int ic = r / 9, k = r - ic * 9;
        wds[o][ic][k] = dw[((size_t)n * 1024 + (size_t)(g * 4 + o) * 4 + ic) * 9 + k];
    }
    if (t >= 192 && t < 208) {
        int u = t - 192;
        wpw[u >> 2][u & 3] = pwk[(size_t)n * 1024 + g * 16 + u];
    }
    if (t >= 224 && t < 228) {
        wb[t - 224] = pwb[(size_t)n * 256 + g * 4 + (t - 224)];
    }

    // staged, normalized, reflection-padded input tile
#pragma unroll
    for (int ic = 0; ic < 4; ++ic) {
        int ci = n * 256 + g * 4 + ic;
        float m = meanv[ci], sc = invv[ci];
        const float* pc = pred + (size_t)ci * HW * HW;
        for (int i = t; i < 66 * 34; i += 256) {
            int iy = i / 34, ix = i - iy * 34;
            int r = ty0 + iy - 1;
            r = (r < 0) ? -r : (r > 127 ? 254 - r : r);
            int q = tx0 + ix - 1;
            q = (q < 0) ? -q : (q > 127 ? 254 - q : q);
            tile[ic][iy][ix] = (pc[r * HW + q] - m) * sc;
        }
    }
    __syncthreads();

    int px = t & 31;
    int rb = t >> 5;     // 0..7 -> rows rb*8 .. rb*8+7

    float y[4][8];
#pragma unroll
    for (int o = 0; o < 4; ++o)
#pragma unroll
        for (int p = 0; p < 8; ++p) y[o][p] = 0.f;

#pragma unroll
    for (int ic = 0; ic < 4; ++ic) {
#pragma unroll
        for (int kw = 0; kw < 3; ++kw) {
            float rv[10];
#pragma unroll
            for (int r = 0; r < 10; ++r) rv[r] = tile[ic][rb * 8 + r][px + kw];
#pragma unroll
            for (int kh = 0; kh < 3; ++kh) {
                float w0 = wds[0][ic][kh * 3 + kw];
                float w1 = wds[1][ic][kh * 3 + kw];
                float w2 = wds[2][ic][kh * 3 + kw];
                float w3 = wds[3][ic][kh * 3 + kw];
#pragma unroll
                for (int p = 0; p < 8; ++p) {
                    float v = rv[p + kh];
                    y[0][p] = fmaf(w0, v, y[0][p]);
                    y[1][p] = fmaf(w1, v, y[1][p]);
                    y[2][p] = fmaf(w2, v, y[2][p]);
                    y[3][p] = fmaf(w3, v, y[3][p]);
                }
            }
        }
    }

    // 1x1 mix + bias + store
#pragma unroll
    for (int o = 0; o < 4; ++o) {
        float p0 = wpw[o][0], p1 = wpw[o][1], p2 = wpw[o][2], p3 = wpw[o][3];
        float bb = wb[o];
        size_t base = (((size_t)n * 256 + g * 4 + o) * HW + (ty0 + rb * 8)) * HW + tx0 + px;
#pragma unroll
        for (int p = 0; p < 8; ++p) {
            float a = fmaf(p0, y[0][p], fmaf(p1, y[1][p], fmaf(p2, y[2][p], fmaf(p3, y[3][p], bb))));
            out[base + (size_t)p * HW] = a;
        }
    }
}

extern "C" void kernel_launch(void* const* d_in, const int* in_sizes, int n_in,
                              void* d_out, int out_size, void* d_ws, size_t ws_size,
                              hipStream_t stream) {
    const float* style = (const float*)d_in[0];   // [8,512,4,4]
    const float* pred  = (const float*)d_in[1];   // [8,256,128,128]
    const float* dww   = (const float*)d_in[2];   // [1024,512,2,2]
    const float* dwb   = (const float*)d_in[3];   // [1024]
    const float* pkw   = (const float*)d_in[4];   // [1024,512]
    const float* pkb   = (const float*)d_in[5];   // [1024]
    const float* pbw   = (const float*)d_in[6];   // [256,512]
    const float* pbb   = (const float*)d_in[7];   // [256]
    float* out = (float*)d_out;

    float* ws      = (float*)d_ws;
    float* s_ws    = ws;            // 4096
    float* dw_ws   = ws + 4096;     // 73728
    float* pwk_ws  = ws + 77824;    // 8192
    float* pwb_ws  = ws + 86016;    // 2048
    float* mean_ws = ws + 88064;    // 2048
    float* inv_ws  = ws + 90112;    // 2048  (end: 92160 floats)

    style_mean_k<<<(NB * SD + 255) / 256, 256, 0, stream>>>(style, s_ws);
    gen_dw_k<<<dim3(1024, NB), 256, 0, stream>>>(style, dww, dwb, dw_ws);
    gen_pw_k<<<(NB * 1280 + 255) / 256, 256, 0, stream>>>(s_ws, pkw, pkb, pbw, pbb,
                                                          pwk_ws, pwb_ws);
    inorm_stats_k<<<NB * CIN, 256, 0, stream>>>(pred, mean_ws, inv_ws);
    adaconv_main_k<<<4096, 256, 0, stream>>>(pred, dw_ws, pwk_ws, pwb_ws,
                                             mean_ws, inv_ws, out);
}

// Round 2
// 168.802 us; speedup vs baseline: 1.0060x; 1.0060x over previous
//
#include <hip/hip_runtime.h>

#define NB 8
#define CIN 256
#define SD 512
#define HW 128
#define EPS 1e-5f

// ---------------- 1. style spatial mean: s[n,c] = mean(style[n,c,:,:]) ----------------
__global__ __launch_bounds__(256) void style_mean_k(const float* __restrict__ style,
                                                    float* __restrict__ s_ws) {
    int u = blockIdx.x * 256 + threadIdx.x;
    if (u >= NB * SD) return;
    const float* p = style + (size_t)u * 16;
    float a = 0.f;
#pragma unroll
    for (int k = 0; k < 16; ++k) a += p[k];
    s_ws[u] = a * (1.f / 16.f);
}

// ---------------- 2. dw kernel generation: dw[n,f,3,3] = conv(style, dw_w) + b --------
// b = f*8 + n : consecutive blocks share the same dww row (L2 reuse).
__global__ __launch_bounds__(256) void gen_dw_k(const float* __restrict__ style,
                                                const float* __restrict__ dww,
                                                const float* __restrict__ dwb,
                                                float* __restrict__ dw) {
    int b = blockIdx.x;
    int n = b & 7, f = b >> 3, t = threadIdx.x;
    float acc[9];
#pragma unroll
    for (int k = 0; k < 9; ++k) acc[k] = 0.f;
    for (int c = t; c < SD; c += 256) {
        const float4* sp = (const float4*)(style + ((size_t)n * SD + c) * 16);
        float st[16];
#pragma unroll
        for (int k = 0; k < 4; ++k) {
            float4 v = sp[k];
            st[k * 4 + 0] = v.x; st[k * 4 + 1] = v.y;
            st[k * 4 + 2] = v.z; st[k * 4 + 3] = v.w;
        }
        float4 w = *(const float4*)(dww + ((size_t)f * SD + c) * 4);
#pragma unroll
        for (int p = 0; p < 3; ++p)
#pragma unroll
            for (int q = 0; q < 3; ++q)
                acc[p * 3 + q] += st[p * 4 + q] * w.x + st[p * 4 + q + 1] * w.y
                                + st[(p + 1) * 4 + q] * w.z + st[(p + 1) * 4 + q + 1] * w.w;
    }
    __shared__ float red[4][9];
#pragma unroll
    for (int k = 0; k < 9; ++k)
#pragma unroll
        for (int off = 32; off; off >>= 1) acc[k] += __shfl_down(acc[k], off);
    if ((t & 63) == 0) {
#pragma unroll
        for (int k = 0; k < 9; ++k) red[t >> 6][k] = acc[k];
    }
    __syncthreads();
    if (t < 9)
        dw[((size_t)n * 1024 + f) * 9 + t] =
            red[0][t] + red[1][t] + red[2][t] + red[3][t] + dwb[f];
}

// ---------------- 3. pointwise kernels + bias: linear layers on s ---------------------
__global__ __launch_bounds__(256) void gen_pw_k(const float* __restrict__ s_ws,
                                                const float* __restrict__ pkw,
                                                const float* __restrict__ pkb,
                                                const float* __restrict__ pbw,
                                                const float* __restrict__ pbb,
                                                float* __restrict__ pwk,
                                                float* __restrict__ pwbias) {
    int u = blockIdx.x * 256 + threadIdx.x;
    if (u >= NB * 1280) return;
    int n = u / 1280;
    int j = u - n * 1280;
    bool isk = j < 1024;
    const float4* sv = (const float4*)(s_ws + (size_t)n * SD);
    const float4* wv = (const float4*)(isk ? (pkw + (size_t)j * SD)
                                           : (pbw + (size_t)(j - 1024) * SD));
    float a = 0.f;
    for (int k = 0; k < SD / 4; ++k) {
        float4 x = sv[k];
        float4 w = wv[k];
        a += x.x * w.x + x.y * w.y + x.z * w.z + x.w * w.w;
    }
    if (isk) pwk[(size_t)n * 1024 + j] = a + pkb[j];
    else     pwbias[(size_t)n * 256 + (j - 1024)] = a + pbb[j - 1024];
}

// ---------------- 4. instance-norm stats: mean & rsqrt(var+eps) per (n,c) -------------
__global__ __launch_bounds__(256) void inorm_stats_k(const float* __restrict__ pred,
                                                     float* __restrict__ meanv,
                                                     float* __restrict__ invv) {
    int bc = blockIdx.x;  // 0..2047 = n*256+c
    int t = threadIdx.x;
    const float4* p = (const float4*)(pred + (size_t)bc * HW * HW);
    float s = 0.f, ss = 0.f;
#pragma unroll
    for (int k = 0; k < 16; ++k) {
        float4 v = p[k * 256 + t];
        s  += v.x + v.y + v.z + v.w;
        ss += v.x * v.x + v.y * v.y + v.z * v.z + v.w * v.w;
    }
#pragma unroll
    for (int off = 32; off; off >>= 1) {
        s  += __shfl_down(s, off);
        ss += __shfl_down(ss, off);
    }
    __shared__ float ws4[4], wss4[4];
    if ((t & 63) == 0) { ws4[t >> 6] = s; wss4[t >> 6] = ss; }
    __syncthreads();
    if (t == 0) {
        float S  = ws4[0] + ws4[1] + ws4[2] + ws4[3];
        float SS = wss4[0] + wss4[1] + wss4[2] + wss4[3];
        float m = S * (1.f / (HW * HW));
        float var = SS * (1.f / (HW * HW)) - m * m;
        meanv[bc] = m;
        invv[bc] = rsqrtf(var + EPS);
    }
}

// ---------------- 5. fold: W[o,ic,k] = sum_i pwk[o,i]*sc[ic]*dw[i,ic,k] (in-place) ----
//                  B[o] = pwbias[o] - sum_i pwk[o,i] * sum_ic m*sc * sum_k dw[i,ic,k]
__global__ __launch_bounds__(192) void fold_k(float* __restrict__ dw_ws,
                                              const float* __restrict__ pwk_ws,
                                              float* __restrict__ pwb_ws,
                                              const float* __restrict__ mean_ws,
                                              const float* __restrict__ inv_ws) {
    __shared__ float dwl[144], pwkl[16], invl[4], msc[4], pwbl[4];
    int b = blockIdx.x;              // n*64+g
    int n = b >> 6, g = b & 63;
    int t = threadIdx.x;
    size_t dbase = (size_t)(n * 1024 + g * 16) * 9;
    if (t < 144) dwl[t] = dw_ws[dbase + t];
    else if (t < 160) pwkl[t - 144] = pwk_ws[(size_t)n * 1024 + g * 16 + (t - 144)];
    else if (t < 164) {
        int ic = t - 160;
        float m = mean_ws[n * 256 + g * 4 + ic];
        float s = inv_ws[n * 256 + g * 4 + ic];
        invl[ic] = s; msc[ic] = m * s;
    } else if (t < 168) {
        pwbl[t - 164] = pwb_ws[n * 256 + g * 4 + (t - 164)];
    }
    __syncthreads();
    if (t < 144) {
        int o = t / 36, rm = t % 36, ic = rm / 9, k = rm % 9;
        float a = 0.f;
#pragma unroll
        for (int i = 0; i < 4; ++i) a += pwkl[o * 4 + i] * dwl[(i * 4 + ic) * 9 + k];
        dw_ws[dbase + (size_t)(o * 4 + ic) * 9 + k] = a * invl[ic];
    } else if (t < 148) {
        int o = t - 144;
        float cb = 0.f;
#pragma unroll
        for (int i = 0; i < 4; ++i) {
            float s2 = 0.f;
#pragma unroll
            for (int ic = 0; ic < 4; ++ic) {
                float sk = 0.f;
#pragma unroll
                for (int k = 0; k < 9; ++k) sk += dwl[(i * 4 + ic) * 9 + k];
                s2 += msc[ic] * sk;
            }
            cb += pwkl[o * 4 + i] * s2;
        }
        pwb_ws[n * 256 + g * 4 + o] = pwbl[o] - cb;
    }
}

// ---------------- 6. fused main: reflect-pad + folded grouped 3x3 -> out --------------
// block = (n, g, 32x32 tile). LDS tile [4][34][35] (~19 KB) -> 8 blocks/CU.
// thread: cq = t&7 (4 cols), r = t>>3 (row). Weights via wave-uniform s_loads.
__global__ __launch_bounds__(256) void adaconv_main_k(const float* __restrict__ pred,
                                                      const float* __restrict__ Wf,
                                                      const float* __restrict__ Bf,
                                                      float* __restrict__ out) {
    __shared__ float tile[4][34][35];
    int b = blockIdx.x;              // 8192 blocks
    int tx0 = (b & 3) << 5;
    int ty0 = ((b >> 2) & 3) << 5;
    int g = (b >> 4) & 63;
    int n = b >> 10;
    int t = threadIdx.x;
    const float* wp = Wf + (size_t)(n * 64 + g) * 144;
    const float* bp = Bf + (size_t)(n * 64 + g) * 4;

    // stage raw pred tile (reflect-padded), float4 interior + scalar halo cols
#pragma unroll
    for (int ic = 0; ic < 4; ++ic) {
        const float* pc = pred + (size_t)(n * 256 + g * 4 + ic) * (HW * HW);
#pragma unroll
        for (int i0 = 0; i0 < 2; ++i0) {
            int i = i0 * 256 + t;
            if (i < 272) {
                int iy = i >> 3, cq = i & 7;
                int r = ty0 + iy - 1;
                r = (r < 0) ? 1 : (r > 127 ? 126 : r);
                float4 v = *(const float4*)(pc + r * HW + tx0 + (cq << 2));
                float* dst = &tile[ic][iy][1 + (cq << 2)];
                dst[0] = v.x; dst[1] = v.y; dst[2] = v.z; dst[3] = v.w;
            }
        }
        if (t < 68) {
            int iy = t >> 1, side = t & 1;
            int r = ty0 + iy - 1;
            r = (r < 0) ? 1 : (r > 127 ? 126 : r);
            int gc = side ? (tx0 + 32) : (tx0 - 1);
            gc = (gc < 0) ? 1 : (gc > 127 ? 126 : gc);
            tile[ic][iy][side ? 33 : 0] = pc[r * HW + gc];
        }
    }
    __syncthreads();

    int cq = t & 7, r = t >> 3;   // out row ty0+r, cols tx0+4cq..+3
    float acc[4][4];
#pragma unroll
    for (int o = 0; o < 4; ++o) {
        float bb = bp[o];
#pragma unroll
        for (int p = 0; p < 4; ++p) acc[o][p] = bb;
    }

#pragma unroll
    for (int ic = 0; ic < 4; ++ic) {
#pragma unroll
        for (int kh = 0; kh < 3; ++kh) {
            float v[6];
            const float* row = &tile[ic][r + kh][cq << 2];
#pragma unroll
            for (int c = 0; c < 6; ++c) v[c] = row[c];
#pragma unroll
            for (int o = 0; o < 4; ++o) {
                float w0 = wp[(o * 4 + ic) * 9 + kh * 3 + 0];
                float w1 = wp[(o * 4 + ic) * 9 + kh * 3 + 1];
                float w2 = wp[(o * 4 + ic) * 9 + kh * 3 + 2];
#pragma unroll
                for (int p = 0; p < 4; ++p)
                    acc[o][p] = fmaf(w0, v[p], fmaf(w1, v[p + 1], fmaf(w2, v[p + 2], acc[o][p])));
            }
        }
    }

#pragma unroll
    for (int o = 0; o < 4; ++o) {
        float4 vv = make_float4(acc[o][0], acc[o][1], acc[o][2], acc[o][3]);
        *(float4*)(out + ((size_t)(n * 256 + g * 4 + o) * HW + ty0 + r) * HW + tx0 + (cq << 2)) = vv;
    }
}

extern "C" void kernel_launch(void* const* d_in, const int* in_sizes, int n_in,
                              void* d_out, int out_size, void* d_ws, size_t ws_size,
                              hipStream_t stream) {
    const float* style = (const float*)d_in[0];   // [8,512,4,4]
    const float* pred  = (const float*)d_in[1];   // [8,256,128,128]
    const float* dww   = (const float*)d_in[2];   // [1024,512,2,2]
    const float* dwb   = (const float*)d_in[3];   // [1024]
    const float* pkw   = (const float*)d_in[4];   // [1024,512]
    const float* pkb   = (const float*)d_in[5];   // [1024]
    const float* pbw   = (const float*)d_in[6];   // [256,512]
    const float* pbb   = (const float*)d_in[7];   // [256]
    float* out = (float*)d_out;

    float* ws      = (float*)d_ws;
    float* s_ws    = ws;            // 4096
    float* dw_ws   = ws + 4096;     // 73728 (becomes folded W in-place)
    float* pwk_ws  = ws + 77824;    // 8192
    float* pwb_ws  = ws + 86016;    // 2048 (becomes folded bias in-place)
    float* mean_ws = ws + 88064;    // 2048
    float* inv_ws  = ws + 90112;    // 2048  (end: 92160 floats)

    style_mean_k<<<(NB * SD + 255) / 256, 256, 0, stream>>>(style, s_ws);
    gen_pw_k<<<(NB * 1280 + 255) / 256, 256, 0, stream>>>(s_ws, pkw, pkb, pbw, pbb,
                                                          pwk_ws, pwb_ws);
    gen_dw_k<<<1024 * NB, 256, 0, stream>>>(style, dww, dwb, dw_ws);
    inorm_stats_k<<<NB * CIN, 256, 0, stream>>>(pred, mean_ws, inv_ws);
    fold_k<<<NB * 64, 192, 0, stream>>>(dw_ws, pwk_ws, pwb_ws, mean_ws, inv_ws);
    adaconv_main_k<<<8192, 256, 0, stream>>>(pred, dw_ws, pwb_ws, out);
}

// Round 3
// 116.887 us; speedup vs baseline: 1.4528x; 1.4441x over previous
//
#include <hip/hip_runtime.h>

#define NB 8
#define SD 512
#define HW 128
#define EPS 1e-5f

__device__ __forceinline__ int refl(int r) { return r < 0 ? 1 : (r > 127 ? 126 : r); }

// ============ prep: [0,2048) inorm stats | [2048,2064) style mean | [2064,4112) gen_dw
__global__ __launch_bounds__(256) void prep_k(const float* __restrict__ pred,
                                              const float* __restrict__ style,
                                              const float* __restrict__ dww,
                                              const float* __restrict__ dwb,
                                              float* __restrict__ s_ws,
                                              float* __restrict__ dw_ws,
                                              float* __restrict__ mean_ws,
                                              float* __restrict__ inv_ws) {
    __shared__ float ws4[4], wss4[4];
    int b = blockIdx.x, t = threadIdx.x;
    if (b < 2048) {
        // ---- instance-norm stats: block per (n,c) ----
        const float4* p = (const float4*)(pred + (size_t)b * HW * HW);
        float s = 0.f, ss = 0.f;
#pragma unroll
        for (int k = 0; k < 16; ++k) {
            float4 v = p[k * 256 + t];
            s  += v.x + v.y + v.z + v.w;
            ss += v.x * v.x + v.y * v.y + v.z * v.z + v.w * v.w;
        }
#pragma unroll
        for (int off = 32; off; off >>= 1) {
            s  += __shfl_down(s, off);
            ss += __shfl_down(ss, off);
        }
        if ((t & 63) == 0) { ws4[t >> 6] = s; wss4[t >> 6] = ss; }
        __syncthreads();
        if (t == 0) {
            float S  = ws4[0] + ws4[1] + ws4[2] + ws4[3];
            float SS = wss4[0] + wss4[1] + wss4[2] + wss4[3];
            float m = S * (1.f / (HW * HW));
            float var = SS * (1.f / (HW * HW)) - m * m;
            mean_ws[b] = m;
            inv_ws[b] = rsqrtf(var + EPS);
        }
    } else if (b < 2064) {
        // ---- style spatial mean ----
        int u = (b - 2048) * 256 + t;
        const float* p = style + (size_t)u * 16;
        float a = 0.f;
#pragma unroll
        for (int k = 0; k < 16; ++k) a += p[k];
        s_ws[u] = a * (1.f / 16.f);
    } else {
        // ---- dw kernel generation: wave per f, 4 f per block sharing style ----
        int bb = b - 2064;               // n fastest -> dww L2 reuse
        int n = bb & 7;
        int f = ((bb >> 3) << 2) + (t >> 6);
        int lane = t & 63;
        float acc[9];
#pragma unroll
        for (int k = 0; k < 9; ++k) acc[k] = 0.f;
#pragma unroll 2
        for (int it = 0; it < 8; ++it) {
            int c = lane + (it << 6);
            const float4* sp = (const float4*)(style + ((size_t)n * SD + c) * 16);
            float st[16];
#pragma unroll
            for (int k = 0; k < 4; ++k) {
                float4 v = sp[k];
                st[k * 4 + 0] = v.x; st[k * 4 + 1] = v.y;
                st[k * 4 + 2] = v.z; st[k * 4 + 3] = v.w;
            }
            float4 w = *(const float4*)(dww + ((size_t)f * SD + c) * 4);
#pragma unroll
            for (int p = 0; p < 3; ++p)
#pragma unroll
                for (int q = 0; q < 3; ++q)
                    acc[p * 3 + q] += st[p * 4 + q] * w.x + st[p * 4 + q + 1] * w.y
                                    + st[(p + 1) * 4 + q] * w.z + st[(p + 1) * 4 + q + 1] * w.w;
        }
#pragma unroll
        for (int k = 0; k < 9; ++k)
#pragma unroll
            for (int off = 32; off; off >>= 1) acc[k] += __shfl_down(acc[k], off);
        if (lane == 0) {
            float bias = dwb[f];
#pragma unroll
            for (int k = 0; k < 9; ++k)
                dw_ws[((size_t)n * 1024 + f) * 9 + k] = acc[k] + bias;
        }
    }
}

// ============ pointwise kernels + bias: one wave per output, coalesced ================
__global__ __launch_bounds__(256) void gen_pw_k(const float* __restrict__ s_ws,
                                                const float* __restrict__ pkw,
                                                const float* __restrict__ pkb,
                                                const float* __restrict__ pbw,
                                                const float* __restrict__ pbb,
                                                float* __restrict__ pwk,
                                                float* __restrict__ pwbias) {
    int w = blockIdx.x * 4 + (threadIdx.x >> 6);   // 0..10239
    int lane = threadIdx.x & 63;
    int n = w / 1280;
    int j = w - n * 1280;
    bool isk = j < 1024;
    const float2* wrow = (const float2*)(isk ? (pkw + (size_t)j * SD)
                                             : (pbw + (size_t)(j - 1024) * SD));
    const float2* s2 = (const float2*)(s_ws + (size_t)n * SD);
    float a = 0.f;
#pragma unroll
    for (int it = 0; it < 4; ++it) {
        int c2 = lane + (it << 6);
        float2 x = s2[c2];
        float2 v = wrow[c2];
        a += x.x * v.x + x.y * v.y;
    }
#pragma unroll
    for (int off = 32; off; off >>= 1) a += __shfl_down(a, off);
    if (lane == 0) {
        if (isk) pwk[(size_t)n * 1024 + j] = a + pkb[j];
        else     pwbias[(size_t)n * 256 + (j - 1024)] = a + pbb[j - 1024];
    }
}

// ============ fused main: inline fold + reflect-pad + grouped 3x3, 4-tile pipeline ====
// block = (n, g, ty-stripe); grid 2048 (fully resident). Register prefetch of tile t+1
// overlaps compute of tile t. LDS ~19.6 KB.
__global__ __launch_bounds__(256) void adaconv_main_k(const float* __restrict__ pred,
                                                      const float* __restrict__ dwr,
                                                      const float* __restrict__ pwk,
                                                      const float* __restrict__ pwb,
                                                      const float* __restrict__ meanv,
                                                      const float* __restrict__ invv,
                                                      float* __restrict__ out) {
    __shared__ float tile[4][34][35];
    __shared__ float wf[4][4][9];
    __shared__ float bf[4];
    int b = blockIdx.x;              // ty fastest, then g, then n
    int ty0 = (b & 3) << 5;
    int g = (b >> 2) & 63;
    int n = b >> 8;
    int t = threadIdx.x;
    const size_t cbase = (size_t)(n * 256 + g * 4);

    float4 pf[5];
    float ph0 = 0.f, ph1 = 0.f;

    auto pref = [&](int tx0) {
#pragma unroll
        for (int k = 0; k < 4; ++k) {
            int j = t + (k << 8);
            int ic = j / 272; int rm = j - ic * 272;
            int iy = rm >> 3, cq = rm & 7;
            int r = refl(ty0 + iy - 1);
            pf[k] = *(const float4*)(pred + (cbase + ic) * (HW * HW) + r * HW + tx0 + (cq << 2));
        }
        if (t < 64) {
            int rm = t + 1024 - 816;     // ic = 3
            int iy = rm >> 3, cq = rm & 7;
            int r = refl(ty0 + iy - 1);
            pf[4] = *(const float4*)(pred + (cbase + 3) * (HW * HW) + r * HW + tx0 + (cq << 2));
        }
        {
            int ic = t / 68; int rm = t - ic * 68;
            int iy = rm >> 1, side = rm & 1;
            int r = refl(ty0 + iy - 1);
            int gc = refl(side ? tx0 + 32 : tx0 - 1);
            ph0 = pred[(cbase + ic) * (HW * HW) + r * HW + gc];
        }
        if (t < 16) {
            int rm = t + 52;             // ic = 3
            int iy = rm >> 1, side = rm & 1;
            int r = refl(ty0 + iy - 1);
            int gc = refl(side ? tx0 + 32 : tx0 - 1);
            ph1 = pred[(cbase + 3) * (HW * HW) + r * HW + gc];
        }
    };

    auto lwrite = [&]() {
#pragma unroll
        for (int k = 0; k < 4; ++k) {
            int j = t + (k << 8);
            int ic = j / 272; int rm = j - ic * 272;
            int iy = rm >> 3, cq = rm & 7;
            float* d = &tile[ic][iy][1 + (cq << 2)];
            d[0] = pf[k].x; d[1] = pf[k].y; d[2] = pf[k].z; d[3] = pf[k].w;
        }
        if (t < 64) {
            int rm = t + 208;
            int iy = rm >> 3, cq = rm & 7;
            float* d = &tile[3][iy][1 + (cq << 2)];
            d[0] = pf[4].x; d[1] = pf[4].y; d[2] = pf[4].z; d[3] = pf[4].w;
        }
        {
            int ic = t / 68; int rm = t - ic * 68;
            tile[ic][rm >> 1][(rm & 1) ? 33 : 0] = ph0;
        }
        if (t < 16) {
            int rm = t + 52;
            tile[3][rm >> 1][(rm & 1) ? 33 : 0] = ph1;
        }
    };

    pref(0);

    // inline fold: W[o,ic,k] = inv[ic] * sum_i pwk[o,i]*dwr[i,ic,k]
    //              B[o] = pwb[o] - sum_i pwk[o,i] * sum_ic mean*inv * sum_k dwr[i,ic,k]
    if (t < 144) {
        int o = t / 36, rm = t % 36, ic = rm / 9, k = rm % 9;
        float a = 0.f;
#pragma unroll
        for (int i = 0; i < 4; ++i)
            a += pwk[n * 1024 + g * 16 + o * 4 + i]
               * dwr[(size_t)(n * 1024 + g * 16 + i * 4 + ic) * 9 + k];
        wf[o][ic][k] = a * invv[cbase + ic];
    } else if (t < 148) {
        int o = t - 144;
        float cb = 0.f;
#pragma unroll
        for (int i = 0; i < 4; ++i) {
            float s2 = 0.f;
#pragma unroll
            for (int ic = 0; ic < 4; ++ic) {
                float sk = 0.f;
#pragma unroll
                for (int k = 0; k < 9; ++k)
                    sk += dwr[(size_t)(n * 1024 + g * 16 + i * 4 + ic) * 9 + k];
                s2 += meanv[cbase + ic] * invv[cbase + ic] * sk;
            }
            cb += pwk[n * 1024 + g * 16 + o * 4 + i] * s2;
        }
        bf[o] = pwb[cbase + o] - cb;
    }

    lwrite();
    __syncthreads();

    int cq = t & 7, r = t >> 3;
#pragma unroll
    for (int tx = 0; tx < 4; ++tx) {
        if (tx < 3) pref((tx + 1) << 5);     // issue next-tile loads (in flight)
        int tx0 = tx << 5;
        float acc[4][4];
#pragma unroll
        for (int o = 0; o < 4; ++o) {
            float bb = bf[o];
#pragma unroll
            for (int p = 0; p < 4; ++p) acc[o][p] = bb;
        }
#pragma unroll
        for (int ic = 0; ic < 4; ++ic) {
#pragma unroll
            for (int kh = 0; kh < 3; ++kh) {
                float v[6];
                const float* row = &tile[ic][r + kh][cq << 2];
#pragma unroll
                for (int c = 0; c < 6; ++c) v[c] = row[c];
#pragma unroll
                for (int o = 0; o < 4; ++o) {
                    float w0 = wf[o][ic][kh * 3 + 0];
                    float w1 = wf[o][ic][kh * 3 + 1];
                    float w2 = wf[o][ic][kh * 3 + 2];
#pragma unroll
                    for (int p = 0; p < 4; ++p)
                        acc[o][p] = fmaf(w0, v[p], fmaf(w1, v[p + 1], fmaf(w2, v[p + 2], acc[o][p])));
                }
            }
        }
#pragma unroll
        for (int o = 0; o < 4; ++o) {
            *(float4*)(out + (cbase + o) * (HW * HW) + (ty0 + r) * HW + tx0 + (cq << 2)) =
                make_float4(acc[o][0], acc[o][1], acc[o][2], acc[o][3]);
        }
        if (tx < 3) {
            __syncthreads();   // all reads of tile done
            lwrite();          // waits on pf vmcnt, writes next tile
            __syncthreads();   // tile ready
        }
    }
}

extern "C" void kernel_launch(void* const* d_in, const int* in_sizes, int n_in,
                              void* d_out, int out_size, void* d_ws, size_t ws_size,
                              hipStream_t stream) {
    const float* style = (const float*)d_in[0];   // [8,512,4,4]
    const float* pred  = (const float*)d_in[1];   // [8,256,128,128]
    const float* dww   = (const float*)d_in[2];   // [1024,512,2,2]
    const float* dwb   = (const float*)d_in[3];   // [1024]
    const float* pkw   = (const float*)d_in[4];   // [1024,512]
    const float* pkb   = (const float*)d_in[5];   // [1024]
    const float* pbw   = (const float*)d_in[6];   // [256,512]
    const float* pbb   = (const float*)d_in[7];   // [256]
    float* out = (float*)d_out;

    float* ws      = (float*)d_ws;
    float* s_ws    = ws;            // 4096
    float* dw_ws   = ws + 4096;     // 73728 (raw generated dw kernels)
    float* pwk_ws  = ws + 77824;    // 8192
    float* pwb_ws  = ws + 86016;    // 2048
    float* mean_ws = ws + 88064;    // 2048
    float* inv_ws  = ws + 90112;    // 2048  (end: 92160 floats)

    prep_k<<<4112, 256, 0, stream>>>(pred, style, dww, dwb, s_ws, dw_ws, mean_ws, inv_ws);
    gen_pw_k<<<2560, 256, 0, stream>>>(s_ws, pkw, pkb, pbw, pbb, pwk_ws, pwb_ws);
    adaconv_main_k<<<2048, 256, 0, stream>>>(pred, dw_ws, pwk_ws, pwb_ws, mean_ws, inv_ws, out);
}